// Round 5
// baseline (227.378 us; speedup 1.0000x reference)
//
#include <hip/hip_runtime.h>
#include <math.h>

#define NHEADS 8
#define DHEAD  64
#define HIDDEN 512     // NHEADS*DHEAD
#define CIN    256
#define NTOK   1024    // 32*32
#define QK_SCALE 10.0f
#define LOG2E 1.44269504088896f

typedef __bf16 bf16x8 __attribute__((ext_vector_type(8)));
typedef float  f32x4  __attribute__((ext_vector_type(4)));
typedef unsigned short u16x8 __attribute__((ext_vector_type(8)));
typedef unsigned short u16x4 __attribute__((ext_vector_type(4)));

__device__ inline unsigned short f2bf(float f) {
    unsigned u = __builtin_bit_cast(unsigned, f);
    u = (u + 0x7FFFu + ((u >> 16) & 1u)) >> 16;   // RNE
    return (unsigned short)u;
}

__device__ inline bf16x8 cvt8(const float* p) {
    float4 a = *(const float4*)p;
    float4 b = *(const float4*)(p + 4);
    u16x8 t;
    t[0] = f2bf(a.x); t[1] = f2bf(a.y); t[2] = f2bf(a.z); t[3] = f2bf(a.w);
    t[4] = f2bf(b.x); t[5] = f2bf(b.y); t[6] = f2bf(b.z); t[7] = f2bf(b.w);
    return __builtin_bit_cast(bf16x8, t);
}

// ---------------------------------------------------------------------------
// x (8,256,1024) fp32 d-major -> xt (8,1024,256) bf16 token-major.
// ---------------------------------------------------------------------------
__global__ __launch_bounds__(256)
void cvt_x_kernel(const float* __restrict__ x, unsigned short* __restrict__ xt) {
    const int b  = blockIdx.z;
    const int c0 = blockIdx.y * 64;
    const int n0 = blockIdx.x * 64;
    const float* src = x + ((size_t)b * CIN + c0) * NTOK + n0;
    unsigned short* dst = xt + ((size_t)b * NTOK + n0) * CIN + c0;

    __shared__ float T[64][65];
    const int t = threadIdx.x;
    {
        const int nq = t & 15, cg = t >> 4;
        #pragma unroll
        for (int rr = 0; rr < 4; ++rr) {
            const int c = cg + rr * 16;
            float4 v = *(const float4*)(src + (size_t)c * NTOK + nq * 4);
            T[c][nq * 4 + 0] = v.x;
            T[c][nq * 4 + 1] = v.y;
            T[c][nq * 4 + 2] = v.z;
            T[c][nq * 4 + 3] = v.w;
        }
    }
    __syncthreads();
    {
        const int n = t >> 2, cq = t & 3;
        alignas(16) unsigned short tmp[16];
        #pragma unroll
        for (int e = 0; e < 16; ++e)
            tmp[e] = f2bf(T[cq * 16 + e][n]);
        *(uint4*)(dst + (size_t)n * CIN + cq * 16)     = *(uint4*)&tmp[0];
        *(uint4*)(dst + (size_t)n * CIN + cq * 16 + 8) = *(uint4*)&tmp[8];
    }
}

// ---------------------------------------------------------------------------
// Weights fp32 -> bf16 (row-major preserved).
// ---------------------------------------------------------------------------
__global__ __launch_bounds__(256)
void cvt_w_kernel(const float* __restrict__ wq, const float* __restrict__ wo,
                  unsigned short* __restrict__ wqb, unsigned short* __restrict__ wob) {
    const size_t i = ((size_t)blockIdx.x * 256 + threadIdx.x) * 8;
    if (i < (size_t)1536 * 256) {
        *(bf16x8*)(wqb + i) = cvt8(wq + i);
    } else {
        const size_t j = i - (size_t)1536 * 256;
        *(bf16x8*)(wob + j) = cvt8(wo + j);
    }
}

// ---------------------------------------------------------------------------
// GEMM1: qkv = w_qkv (1536x256) x x (256x1024) per batch, bf16 MFMA.
// Epilogues: q/k -> token-major fp32 qt + sumsq atomics; v -> bf16 d-major vb.
// ---------------------------------------------------------------------------
__global__ __launch_bounds__(256)
void gemm1_kernel(const unsigned short* __restrict__ wqb,
                  const unsigned short* __restrict__ xt,
                  float* __restrict__ qt,
                  unsigned short* __restrict__ vb,
                  float* __restrict__ ss) {
    const int b  = blockIdx.z;
    const int bm = blockIdx.y * 128;
    const int bn = blockIdx.x * 128;
    const int wave = threadIdx.x >> 6, lane = threadIdx.x & 63;
    const int lo = lane & 15, hi = lane >> 4;
    const int wm = bm + (wave >> 1) * 64;
    const int wn = bn + (wave & 1) * 64;

    const unsigned short* Ab = wqb + (size_t)(wm + lo) * CIN + hi * 8;
    const unsigned short* Bb = xt + ((size_t)b * NTOK + wn + lo) * CIN + hi * 8;

    f32x4 acc[4][4];
    #pragma unroll
    for (int mi = 0; mi < 4; ++mi)
        #pragma unroll
        for (int ni = 0; ni < 4; ++ni) acc[mi][ni] = (f32x4){0.f, 0.f, 0.f, 0.f};

    for (int k0 = 0; k0 < CIN; k0 += 32) {
        bf16x8 a[4], bf[4];
        #pragma unroll
        for (int mi = 0; mi < 4; ++mi) a[mi]  = *(const bf16x8*)(Ab + (size_t)mi * 16 * CIN + k0);
        #pragma unroll
        for (int ni = 0; ni < 4; ++ni) bf[ni] = *(const bf16x8*)(Bb + (size_t)ni * 16 * CIN + k0);
        #pragma unroll
        for (int mi = 0; mi < 4; ++mi)
            #pragma unroll
            for (int ni = 0; ni < 4; ++ni)
                acc[mi][ni] = __builtin_amdgcn_mfma_f32_16x16x32_bf16(a[mi], bf[ni], acc[mi][ni], 0, 0, 0);
    }

    __shared__ unsigned short VL[4][32][72];

    if (bm < 1024) {
        const int isK = (wm >= 512) ? 1 : 0;
        const int ch0 = wm & 511;
        const int head = ch0 >> 6;
        float* dst = qt + (((size_t)isK * 64 + b * 8 + head) * NTOK) * DHEAD;
        #pragma unroll
        for (int mi = 0; mi < 4; ++mi) {
            const int d = mi * 16 + hi * 4;
            #pragma unroll
            for (int ni = 0; ni < 4; ++ni) {
                const int n = wn + ni * 16 + lo;
                *(f32x4*)(dst + (size_t)n * DHEAD + d) = acc[mi][ni];
            }
        }
        float p[4][4];
        #pragma unroll
        for (int mi = 0; mi < 4; ++mi)
            #pragma unroll
            for (int r = 0; r < 4; ++r) {
                float s = 0.f;
                #pragma unroll
                for (int ni = 0; ni < 4; ++ni) s += acc[mi][ni][r] * acc[mi][ni][r];
                p[mi][r] = s;
            }
        #pragma unroll
        for (int off = 1; off < 16; off <<= 1)
            #pragma unroll
            for (int mi = 0; mi < 4; ++mi)
                #pragma unroll
                for (int r = 0; r < 4; ++r)
                    p[mi][r] += __shfl_xor(p[mi][r], off, 64);
        if (lo == 0) {
            #pragma unroll
            for (int mi = 0; mi < 4; ++mi)
                #pragma unroll
                for (int r = 0; r < 4; ++r)
                    atomicAdd(&ss[(size_t)b * 1024 + isK * 512 + ch0 + mi * 16 + hi * 4 + r], p[mi][r]);
        }
    } else {
        const int ch0 = wm - 1024;
        #pragma unroll
        for (int half = 0; half < 2; ++half) {
            #pragma unroll
            for (int mm = 0; mm < 2; ++mm) {
                const int mi = half * 2 + mm;
                #pragma unroll
                for (int ni = 0; ni < 4; ++ni)
                    #pragma unroll
                    for (int r = 0; r < 4; ++r)
                        VL[wave][mm * 16 + hi * 4 + r][ni * 16 + lo] = f2bf(acc[mi][ni][r]);
            }
            #pragma unroll
            for (int i = 0; i < 4; ++i) {
                const int flat = i * 64 + lane;
                const int row = flat >> 3, c = flat & 7;
                uint4 v = *(uint4*)&VL[wave][row][c * 8];
                const int ch = ch0 + half * 32 + row;
                *(uint4*)(vb + ((size_t)b * HIDDEN + ch) * NTOK + wn + c * 8) = v;
            }
        }
    }
}

// ---------------------------------------------------------------------------
// qt fp32 [isK][bh][n][d] -> qs/ks bf16 [bh][n][d], scaled by rsqrt(ss) (x10 q).
// ---------------------------------------------------------------------------
__global__ __launch_bounds__(256)
void scale_cvt_kernel(const float* __restrict__ qt, const float* __restrict__ ss,
                      unsigned short* __restrict__ qs, unsigned short* __restrict__ ks) {
    const size_t idx = ((size_t)blockIdx.x * 256 + threadIdx.x) * 8;
    const size_t half = (size_t)64 * NTOK * DHEAD;
    const int isK = idx >= half;
    const size_t rem = idx - (size_t)isK * half;
    const int bh = (int)(rem >> 16);
    const int d0 = (int)(rem & 63);
    const int b  = bh >> 3;
    const int ch = isK * 512 + (bh & 7) * 64 + d0;
    const float scl = isK ? 1.0f : QK_SCALE;

    const float* ip = qt + idx;
    float4 v0 = *(const float4*)ip;
    float4 v1 = *(const float4*)(ip + 4);
    float4 q0 = *(const float4*)(ss + (size_t)b * 1024 + ch);
    float4 q1 = *(const float4*)(ss + (size_t)b * 1024 + ch + 4);
    float4 s0, s1;
    s0.x = 1.0f / fmaxf(sqrtf(q0.x), 1e-12f); s0.y = 1.0f / fmaxf(sqrtf(q0.y), 1e-12f);
    s0.z = 1.0f / fmaxf(sqrtf(q0.z), 1e-12f); s0.w = 1.0f / fmaxf(sqrtf(q0.w), 1e-12f);
    s1.x = 1.0f / fmaxf(sqrtf(q1.x), 1e-12f); s1.y = 1.0f / fmaxf(sqrtf(q1.y), 1e-12f);
    s1.z = 1.0f / fmaxf(sqrtf(q1.z), 1e-12f); s1.w = 1.0f / fmaxf(sqrtf(q1.w), 1e-12f);
    u16x8 t;
    t[0] = f2bf(v0.x * s0.x * scl); t[1] = f2bf(v0.y * s0.y * scl);
    t[2] = f2bf(v0.z * s0.z * scl); t[3] = f2bf(v0.w * s0.w * scl);
    t[4] = f2bf(v1.x * s1.x * scl); t[5] = f2bf(v1.y * s1.y * scl);
    t[6] = f2bf(v1.z * s1.z * scl); t[7] = f2bf(v1.w * s1.w * scl);
    *(u16x8*)((isK ? ks : qs) + rem) = t;
}

// ---------------------------------------------------------------------------
// MFMA flash attention, split-K over keys (2 splits x 512 keys).
// 32 q-rows/wave, j-block 64, no barriers in the main loop.
// Partials: po fp32 [split][bh][row][d] (unnormalized), pml {m,l} per row.
// ---------------------------------------------------------------------------
__global__ __launch_bounds__(256)
void attn_mfma_kernel(const unsigned short* __restrict__ qs,
                      const unsigned short* __restrict__ ks,
                      const unsigned short* __restrict__ vb,
                      float* __restrict__ po, float* __restrict__ pml) {
    const int hw = blockIdx.x;                    // 1024 blocks
    const int virt = (hw & 7) * 128 + (hw >> 3);  // XCD-chunked: 8 bh per XCD
    const int bh = virt >> 4;
    const int sub = virt & 15;
    const int it = sub & 7;
    const int js = sub >> 3;                      // key-split index
    const int b = bh >> 3, h = bh & 7;

    const int lane = threadIdx.x & 63;
    const int wave = threadIdx.x >> 6;
    const int lo = lane & 15;
    const int hi = lane >> 4;
    const int iw = it * 128 + wave * 32;

    const unsigned short* qbh = qs + (size_t)bh * NTOK * DHEAD;
    const unsigned short* kbh = ks + (size_t)bh * NTOK * DHEAD;
    const unsigned short* vbh = vb + ((size_t)b * HIDDEN + h * DHEAD) * NTOK;

    __shared__ unsigned short Plds[4][2048];      // 32x64 bf16 per wave, swizzled
    __shared__ float Tlds[4][16][68];             // epilogue transpose
    char* pbase = (char*)&Plds[wave][0];

    bf16x8 aQ[2][2];
    #pragma unroll
    for (int f = 0; f < 2; ++f) {
        const unsigned short* qp = qbh + (size_t)(iw + f * 16 + lo) * DHEAD + hi * 8;
        aQ[f][0] = *(const bf16x8*)qp;
        aQ[f][1] = *(const bf16x8*)(qp + 32);
    }

    float m_r[2][4], l_r[2][4];
    #pragma unroll
    for (int f = 0; f < 2; ++f)
        #pragma unroll
        for (int r = 0; r < 4; ++r) { m_r[f][r] = -INFINITY; l_r[f][r] = 0.0f; }
    f32x4 acc[2][4];
    #pragma unroll
    for (int f = 0; f < 2; ++f)
        #pragma unroll
        for (int ds = 0; ds < 4; ++ds) acc[f][ds] = (f32x4){0.f, 0.f, 0.f, 0.f};

    for (int jt = 0; jt < 8; ++jt) {
        const int j0 = js * 512 + jt * 64;

        // --- V fragment loads issued EARLY (independent of QK/softmax)
        bf16x8 bV[4][2];
        #pragma unroll
        for (int ds = 0; ds < 4; ++ds) {
            const unsigned short* vp = vbh + (size_t)(ds * 16 + lo) * NTOK + j0 + hi * 8;
            bV[ds][0] = *(const bf16x8*)vp;
            bV[ds][1] = *(const bf16x8*)(vp + 32);
        }

        // --- QK^T: sim 32x64 per wave
        f32x4 s[2][4];
        #pragma unroll
        for (int jj = 0; jj < 4; ++jj) {
            const unsigned short* kp = kbh + (size_t)(j0 + jj * 16 + lo) * DHEAD + hi * 8;
            const bf16x8 bK0 = *(const bf16x8*)kp;
            const bf16x8 bK1 = *(const bf16x8*)(kp + 32);
            __builtin_amdgcn_s_setprio(1);
            #pragma unroll
            for (int f = 0; f < 2; ++f) {
                f32x4 c = (f32x4){0.f, 0.f, 0.f, 0.f};
                c = __builtin_amdgcn_mfma_f32_16x16x32_bf16(aQ[f][0], bK0, c, 0, 0, 0);
                c = __builtin_amdgcn_mfma_f32_16x16x32_bf16(aQ[f][1], bK1, c, 0, 0, 0);
                s[f][jj] = c;
            }
            __builtin_amdgcn_s_setprio(0);
        }

        // --- online softmax
        #pragma unroll
        for (int f = 0; f < 2; ++f) {
            float mt[4];
            #pragma unroll
            for (int r = 0; r < 4; ++r)
                mt[r] = fmaxf(fmaxf(s[f][0][r], s[f][1][r]), fmaxf(s[f][2][r], s[f][3][r]));
            #pragma unroll
            for (int off = 1; off < 16; off <<= 1)
                #pragma unroll
                for (int r = 0; r < 4; ++r)
                    mt[r] = fmaxf(mt[r], __shfl_xor(mt[r], off, 64));

            float corr[4];
            #pragma unroll
            for (int r = 0; r < 4; ++r) {
                const float mn = fmaxf(m_r[f][r], mt[r]);
                corr[r] = __builtin_amdgcn_exp2f((m_r[f][r] - mn) * LOG2E);
                m_r[f][r] = mn;
            }
            float rs[4] = {0.f, 0.f, 0.f, 0.f};
            #pragma unroll
            for (int jj = 0; jj < 4; ++jj)
                #pragma unroll
                for (int r = 0; r < 4; ++r) {
                    const float pp = __builtin_amdgcn_exp2f((s[f][jj][r] - m_r[f][r]) * LOG2E);
                    s[f][jj][r] = pp;
                    rs[r] += pp;
                }
            #pragma unroll
            for (int off = 1; off < 16; off <<= 1)
                #pragma unroll
                for (int r = 0; r < 4; ++r)
                    rs[r] += __shfl_xor(rs[r], off, 64);
            #pragma unroll
            for (int r = 0; r < 4; ++r) l_r[f][r] = l_r[f][r] * corr[r] + rs[r];
            #pragma unroll
            for (int ds = 0; ds < 4; ++ds)
                #pragma unroll
                for (int r = 0; r < 4; ++r)
                    acc[f][ds][r] *= corr[r];

            // P -> LDS (bf16, swizzled)
            #pragma unroll
            for (int jj = 0; jj < 4; ++jj)
                #pragma unroll
                for (int r = 0; r < 4; ++r) {
                    const int row = f * 16 + hi * 4 + r;
                    const int byte = (row * 128 + (jj * 16 + lo) * 2) ^ ((row & 7) << 4);
                    *(unsigned short*)(pbase + byte) = f2bf(s[f][jj][r]);
                }
        }

        // --- P A-fragments + PV
        bf16x8 aP[2][2];
        #pragma unroll
        for (int f = 0; f < 2; ++f) {
            const int row = f * 16 + lo;
            const int swz = (lo & 7) << 4;
            aP[f][0] = *(const bf16x8*)(pbase + ((row * 128 + hi * 16) ^ swz));
            aP[f][1] = *(const bf16x8*)(pbase + ((row * 128 + 64 + hi * 16) ^ swz));
        }
        __builtin_amdgcn_s_setprio(1);
        #pragma unroll
        for (int ds = 0; ds < 4; ++ds)
            #pragma unroll
            for (int f = 0; f < 2; ++f) {
                acc[f][ds] = __builtin_amdgcn_mfma_f32_16x16x32_bf16(aP[f][0], bV[ds][0], acc[f][ds], 0, 0, 0);
                acc[f][ds] = __builtin_amdgcn_mfma_f32_16x16x32_bf16(aP[f][1], bV[ds][1], acc[f][ds], 0, 0, 0);
            }
        __builtin_amdgcn_s_setprio(0);
    }

    // --- epilogue: store UNNORMALIZED partials + {m,l}
    float* pob = po + ((size_t)(js * 64 + bh) * NTOK + iw) * DHEAD;
    #pragma unroll
    for (int f = 0; f < 2; ++f) {
        #pragma unroll
        for (int ds = 0; ds < 4; ++ds)
            #pragma unroll
            for (int r = 0; r < 4; ++r)
                Tlds[wave][hi * 4 + r][ds * 16 + lo] = acc[f][ds][r];
        // wave-synchronous readback: fully-coalesced float4 rows
        #pragma unroll
        for (int pass = 0; pass < 4; ++pass) {
            const int flat = pass * 64 + lane;
            const int row = flat >> 4, dq = flat & 15;
            float4 v = *(float4*)&Tlds[wave][row][dq * 4];
            *(float4*)(pob + (size_t)(f * 16 + row) * DHEAD + dq * 4) = v;
        }
        if (lo == 0) {
            #pragma unroll
            for (int r = 0; r < 4; ++r) {
                const int row = iw + f * 16 + hi * 4 + r;
                float2 ml = make_float2(m_r[f][r], l_r[f][r]);
                *(float2*)(pml + ((size_t)(js * 64 + bh) * NTOK + row) * 2) = ml;
            }
        }
    }
}

// ---------------------------------------------------------------------------
// Combine the two key-split partials -> attn_t bf16 token-major [b][n][512].
// ---------------------------------------------------------------------------
__global__ __launch_bounds__(256)
void combine_kernel(const float* __restrict__ po, const float* __restrict__ pml,
                    unsigned short* __restrict__ attn_t) {
    const size_t fl = ((size_t)blockIdx.x * 256 + threadIdx.x) * 4;
    const int bh  = (int)(fl >> 16);
    const int rem = (int)(fl & 65535);
    const int row = rem >> 6;
    const int d   = rem & 63;
    const int b = bh >> 3, h = bh & 7;
    const size_t SS = (size_t)64 * NTOK * DHEAD;

    const float2 ml1 = *(const float2*)(pml + ((size_t)bh * NTOK + row) * 2);
    const float2 ml2 = *(const float2*)(pml + ((size_t)(64 + bh) * NTOK + row) * 2);
    const float M  = fmaxf(ml1.x, ml2.x);
    const float w1 = __builtin_amdgcn_exp2f((ml1.x - M) * LOG2E);
    const float w2 = __builtin_amdgcn_exp2f((ml2.x - M) * LOG2E);
    const float inv = 1.0f / (ml1.y * w1 + ml2.y * w2);

    const float4 o1 = *(const float4*)(po + fl);
    const float4 o2 = *(const float4*)(po + SS + fl);
    u16x4 r;
    r[0] = f2bf((o1.x * w1 + o2.x * w2) * inv);
    r[1] = f2bf((o1.y * w1 + o2.y * w2) * inv);
    r[2] = f2bf((o1.z * w1 + o2.z * w2) * inv);
    r[3] = f2bf((o1.w * w1 + o2.w * w2) * inv);
    *(u16x4*)(attn_t + ((size_t)b * NTOK + row) * HIDDEN + h * DHEAD + d) = r;
}

// ---------------------------------------------------------------------------
// GEMM2: out = w_out (256x512) x attn_t^T + bias, bf16 MFMA.
// ---------------------------------------------------------------------------
__global__ __launch_bounds__(128)
void gemm2_kernel(const unsigned short* __restrict__ wob,
                  const unsigned short* __restrict__ attn_t,
                  const float* __restrict__ b_out,
                  float* __restrict__ out) {
    const int b  = blockIdx.z;
    const int bm = blockIdx.y * 64;
    const int bn = blockIdx.x * 128;
    const int wave = threadIdx.x >> 6, lane = threadIdx.x & 63;
    const int lo = lane & 15, hi = lane >> 4;
    const int wn = bn + wave * 64;

    const unsigned short* Ab = wob + (size_t)(bm + lo) * HIDDEN + hi * 8;
    const unsigned short* Bb = attn_t + ((size_t)b * NTOK + wn + lo) * HIDDEN + hi * 8;

    f32x4 acc[4][4];
    #pragma unroll
    for (int mi = 0; mi < 4; ++mi)
        #pragma unroll
        for (int ni = 0; ni < 4; ++ni) acc[mi][ni] = (f32x4){0.f, 0.f, 0.f, 0.f};

    for (int k0 = 0; k0 < HIDDEN; k0 += 32) {
        bf16x8 a[4], bf[4];
        #pragma unroll
        for (int mi = 0; mi < 4; ++mi) a[mi]  = *(const bf16x8*)(Ab + (size_t)mi * 16 * HIDDEN + k0);
        #pragma unroll
        for (int ni = 0; ni < 4; ++ni) bf[ni] = *(const bf16x8*)(Bb + (size_t)ni * 16 * HIDDEN + k0);
        #pragma unroll
        for (int mi = 0; mi < 4; ++mi)
            #pragma unroll
            for (int ni = 0; ni < 4; ++ni)
                acc[mi][ni] = __builtin_amdgcn_mfma_f32_16x16x32_bf16(a[mi], bf[ni], acc[mi][ni], 0, 0, 0);
    }

    __shared__ float OL[2][32][69];
    #pragma unroll
    for (int half = 0; half < 2; ++half) {
        #pragma unroll
        for (int mm = 0; mm < 2; ++mm) {
            const int mi = half * 2 + mm;
            #pragma unroll
            for (int ni = 0; ni < 4; ++ni)
                #pragma unroll
                for (int r = 0; r < 4; ++r)
                    OL[wave][mm * 16 + hi * 4 + r][ni * 16 + lo] = acc[mi][ni][r];
        }
        #pragma unroll
        for (int i = 0; i < 8; ++i) {
            const int flat = i * 64 + lane;
            const int row = flat >> 4, c = flat & 15;
            float4 v = *(float4*)&OL[wave][row][c * 4];
            const int m = bm + half * 32 + row;
            const float bb = b_out[m];
            v.x += bb; v.y += bb; v.z += bb; v.w += bb;
            *(float4*)(out + ((size_t)b * CIN + m) * NTOK + wn + c * 4) = v;
        }
    }
}

// ---------------------------------------------------------------------------
// Launcher. WS layout (65.1 MB peak):
//  xt @0 (4.19M) | wqb @4194304 | wob @4980736 | ss @5242880 (32K) |
//  qs @5308416 (8.39M, attn_t aliased after attn) | ks @13697024 (8.39M) |
//  vb @22085632 (8.39M) | qt @30474240 (33.55M, po aliased after scale_cvt) |
//  pml @64028672 (1.05M)
// ---------------------------------------------------------------------------
extern "C" void kernel_launch(void* const* d_in, const int* in_sizes, int n_in,
                              void* d_out, int out_size, void* d_ws, size_t ws_size,
                              hipStream_t stream) {
    const float* x     = (const float*)d_in[0];
    const float* w_qkv = (const float*)d_in[1];
    const float* w_out = (const float*)d_in[2];
    const float* b_out = (const float*)d_in[3];
    float* out = (float*)d_out;

    char* ws = (char*)d_ws;
    unsigned short* xt  = (unsigned short*)(ws);
    unsigned short* wqb = (unsigned short*)(ws + 4194304);
    unsigned short* wob = (unsigned short*)(ws + 4980736);
    float*          ss  = (float*)(ws + 5242880);
    unsigned short* qs  = (unsigned short*)(ws + 5308416);
    unsigned short* ks  = (unsigned short*)(ws + 13697024);
    unsigned short* vb  = (unsigned short*)(ws + 22085632);
    float*          qt  = (float*)(ws + 30474240);
    float*          po  = (float*)(ws + 30474240);               // aliases qt (dead)
    unsigned short* attn_t = (unsigned short*)(ws + 5308416);    // aliases qs (dead)
    float*          pml = (float*)(ws + 64028672);

    hipMemsetAsync(ss, 0, 8 * 1024 * sizeof(float), stream);

    cvt_x_kernel<<<dim3(16, 4, 8), 256, 0, stream>>>(x, xt);
    cvt_w_kernel<<<256, 256, 0, stream>>>(w_qkv, w_out, wqb, wob);

    gemm1_kernel<<<dim3(8, 12, 8), 256, 0, stream>>>(wqb, xt, qt, vb, ss);

    scale_cvt_kernel<<<4096, 256, 0, stream>>>(qt, ss, qs, ks);

    attn_mfma_kernel<<<1024, 256, 0, stream>>>(qs, ks, vb, po, pml);

    combine_kernel<<<4096, 256, 0, stream>>>(po, pml, attn_t);

    gemm2_kernel<<<dim3(8, 4, 8), 128, 0, stream>>>(wob, attn_t, b_out, out);
}

// Round 6
// 203.105 us; speedup vs baseline: 1.1195x; 1.1195x over previous
//
#include <hip/hip_runtime.h>
#include <math.h>

#define NHEADS 8
#define DHEAD  64
#define HIDDEN 512     // NHEADS*DHEAD
#define CIN    256
#define NTOK   1024    // 32*32
#define QK_SCALE 10.0f
#define LOG2E 1.44269504088896f
// softmax shift: sim = 10*cos(q,k) <= ~10.1 (bf16 slack); constant shift is exact
#define MSHIFT 10.5f
#define MBIAS  (-MSHIFT * LOG2E)

typedef __bf16 bf16x8 __attribute__((ext_vector_type(8)));
typedef float  f32x4  __attribute__((ext_vector_type(4)));
typedef unsigned short u16x8 __attribute__((ext_vector_type(8)));
typedef unsigned short u16x4 __attribute__((ext_vector_type(4)));

__device__ inline unsigned short f2bf(float f) {
    unsigned u = __builtin_bit_cast(unsigned, f);
    u = (u + 0x7FFFu + ((u >> 16) & 1u)) >> 16;   // RNE
    return (unsigned short)u;
}

__device__ inline bf16x8 cvt8(const float* p) {
    float4 a = *(const float4*)p;
    float4 b = *(const float4*)(p + 4);
    u16x8 t;
    t[0] = f2bf(a.x); t[1] = f2bf(a.y); t[2] = f2bf(a.z); t[3] = f2bf(a.w);
    t[4] = f2bf(b.x); t[5] = f2bf(b.y); t[6] = f2bf(b.z); t[7] = f2bf(b.w);
    return __builtin_bit_cast(bf16x8, t);
}

// ---------------------------------------------------------------------------
// x (8,256,1024) fp32 d-major -> xt (8,1024,256) bf16 token-major.
// ---------------------------------------------------------------------------
__global__ __launch_bounds__(256)
void cvt_x_kernel(const float* __restrict__ x, unsigned short* __restrict__ xt) {
    const int b  = blockIdx.z;
    const int c0 = blockIdx.y * 64;
    const int n0 = blockIdx.x * 64;
    const float* src = x + ((size_t)b * CIN + c0) * NTOK + n0;
    unsigned short* dst = xt + ((size_t)b * NTOK + n0) * CIN + c0;

    __shared__ float T[64][65];
    const int t = threadIdx.x;
    {
        const int nq = t & 15, cg = t >> 4;
        #pragma unroll
        for (int rr = 0; rr < 4; ++rr) {
            const int c = cg + rr * 16;
            float4 v = *(const float4*)(src + (size_t)c * NTOK + nq * 4);
            T[c][nq * 4 + 0] = v.x;
            T[c][nq * 4 + 1] = v.y;
            T[c][nq * 4 + 2] = v.z;
            T[c][nq * 4 + 3] = v.w;
        }
    }
    __syncthreads();
    {
        const int n = t >> 2, cq = t & 3;
        alignas(16) unsigned short tmp[16];
        #pragma unroll
        for (int e = 0; e < 16; ++e)
            tmp[e] = f2bf(T[cq * 16 + e][n]);
        *(uint4*)(dst + (size_t)n * CIN + cq * 16)     = *(uint4*)&tmp[0];
        *(uint4*)(dst + (size_t)n * CIN + cq * 16 + 8) = *(uint4*)&tmp[8];
    }
}

// ---------------------------------------------------------------------------
// Weights fp32 -> bf16 (row-major preserved).
// ---------------------------------------------------------------------------
__global__ __launch_bounds__(256)
void cvt_w_kernel(const float* __restrict__ wq, const float* __restrict__ wo,
                  unsigned short* __restrict__ wqb, unsigned short* __restrict__ wob) {
    const size_t i = ((size_t)blockIdx.x * 256 + threadIdx.x) * 8;
    if (i < (size_t)1536 * 256) {
        *(bf16x8*)(wqb + i) = cvt8(wq + i);
    } else {
        const size_t j = i - (size_t)1536 * 256;
        *(bf16x8*)(wob + j) = cvt8(wo + j);
    }
}

// ---------------------------------------------------------------------------
// GEMM1: qkv = w_qkv (1536x256) x x (256x1024) per batch, bf16 MFMA.
// Epilogues: q/k -> token-major fp32 qt + sumsq atomics; v -> bf16 d-major vb.
// ---------------------------------------------------------------------------
__global__ __launch_bounds__(256)
void gemm1_kernel(const unsigned short* __restrict__ wqb,
                  const unsigned short* __restrict__ xt,
                  float* __restrict__ qt,
                  unsigned short* __restrict__ vb,
                  float* __restrict__ ss) {
    const int b  = blockIdx.z;
    const int bm = blockIdx.y * 128;
    const int bn = blockIdx.x * 128;
    const int wave = threadIdx.x >> 6, lane = threadIdx.x & 63;
    const int lo = lane & 15, hi = lane >> 4;
    const int wm = bm + (wave >> 1) * 64;
    const int wn = bn + (wave & 1) * 64;

    const unsigned short* Ab = wqb + (size_t)(wm + lo) * CIN + hi * 8;
    const unsigned short* Bb = xt + ((size_t)b * NTOK + wn + lo) * CIN + hi * 8;

    f32x4 acc[4][4];
    #pragma unroll
    for (int mi = 0; mi < 4; ++mi)
        #pragma unroll
        for (int ni = 0; ni < 4; ++ni) acc[mi][ni] = (f32x4){0.f, 0.f, 0.f, 0.f};

    for (int k0 = 0; k0 < CIN; k0 += 32) {
        bf16x8 a[4], bf[4];
        #pragma unroll
        for (int mi = 0; mi < 4; ++mi) a[mi]  = *(const bf16x8*)(Ab + (size_t)mi * 16 * CIN + k0);
        #pragma unroll
        for (int ni = 0; ni < 4; ++ni) bf[ni] = *(const bf16x8*)(Bb + (size_t)ni * 16 * CIN + k0);
        #pragma unroll
        for (int mi = 0; mi < 4; ++mi)
            #pragma unroll
            for (int ni = 0; ni < 4; ++ni)
                acc[mi][ni] = __builtin_amdgcn_mfma_f32_16x16x32_bf16(a[mi], bf[ni], acc[mi][ni], 0, 0, 0);
    }

    __shared__ unsigned short VL[4][32][72];

    if (bm < 1024) {
        const int isK = (wm >= 512) ? 1 : 0;
        const int ch0 = wm & 511;
        const int head = ch0 >> 6;
        float* dst = qt + (((size_t)isK * 64 + b * 8 + head) * NTOK) * DHEAD;
        #pragma unroll
        for (int mi = 0; mi < 4; ++mi) {
            const int d = mi * 16 + hi * 4;
            #pragma unroll
            for (int ni = 0; ni < 4; ++ni) {
                const int n = wn + ni * 16 + lo;
                *(f32x4*)(dst + (size_t)n * DHEAD + d) = acc[mi][ni];
            }
        }
        float p[4][4];
        #pragma unroll
        for (int mi = 0; mi < 4; ++mi)
            #pragma unroll
            for (int r = 0; r < 4; ++r) {
                float s = 0.f;
                #pragma unroll
                for (int ni = 0; ni < 4; ++ni) s += acc[mi][ni][r] * acc[mi][ni][r];
                p[mi][r] = s;
            }
        #pragma unroll
        for (int off = 1; off < 16; off <<= 1)
            #pragma unroll
            for (int mi = 0; mi < 4; ++mi)
                #pragma unroll
                for (int r = 0; r < 4; ++r)
                    p[mi][r] += __shfl_xor(p[mi][r], off, 64);
        if (lo == 0) {
            #pragma unroll
            for (int mi = 0; mi < 4; ++mi)
                #pragma unroll
                for (int r = 0; r < 4; ++r)
                    atomicAdd(&ss[(size_t)b * 1024 + isK * 512 + ch0 + mi * 16 + hi * 4 + r], p[mi][r]);
        }
    } else {
        const int ch0 = wm - 1024;
        #pragma unroll
        for (int half = 0; half < 2; ++half) {
            #pragma unroll
            for (int mm = 0; mm < 2; ++mm) {
                const int mi = half * 2 + mm;
                #pragma unroll
                for (int ni = 0; ni < 4; ++ni)
                    #pragma unroll
                    for (int r = 0; r < 4; ++r)
                        VL[wave][mm * 16 + hi * 4 + r][ni * 16 + lo] = f2bf(acc[mi][ni][r]);
            }
            #pragma unroll
            for (int i = 0; i < 4; ++i) {
                const int flat = i * 64 + lane;
                const int row = flat >> 3, c = flat & 7;
                uint4 v = *(uint4*)&VL[wave][row][c * 8];
                const int ch = ch0 + half * 32 + row;
                *(uint4*)(vb + ((size_t)b * HIDDEN + ch) * NTOK + wn + c * 8) = v;
            }
        }
    }
}

// ---------------------------------------------------------------------------
// qt fp32 [isK][bh][n][d] -> qs/ks bf16 [bh][n][d], scaled by rsqrt(ss) (x10 q).
// ---------------------------------------------------------------------------
__global__ __launch_bounds__(256)
void scale_cvt_kernel(const float* __restrict__ qt, const float* __restrict__ ss,
                      unsigned short* __restrict__ qs, unsigned short* __restrict__ ks) {
    const size_t idx = ((size_t)blockIdx.x * 256 + threadIdx.x) * 8;
    const size_t half = (size_t)64 * NTOK * DHEAD;
    const int isK = idx >= half;
    const size_t rem = idx - (size_t)isK * half;
    const int bh = (int)(rem >> 16);
    const int d0 = (int)(rem & 63);
    const int b  = bh >> 3;
    const int ch = isK * 512 + (bh & 7) * 64 + d0;
    const float scl = isK ? 1.0f : QK_SCALE;

    const float* ip = qt + idx;
    float4 v0 = *(const float4*)ip;
    float4 v1 = *(const float4*)(ip + 4);
    float4 q0 = *(const float4*)(ss + (size_t)b * 1024 + ch);
    float4 q1 = *(const float4*)(ss + (size_t)b * 1024 + ch + 4);
    float4 s0, s1;
    s0.x = 1.0f / fmaxf(sqrtf(q0.x), 1e-12f); s0.y = 1.0f / fmaxf(sqrtf(q0.y), 1e-12f);
    s0.z = 1.0f / fmaxf(sqrtf(q0.z), 1e-12f); s0.w = 1.0f / fmaxf(sqrtf(q0.w), 1e-12f);
    s1.x = 1.0f / fmaxf(sqrtf(q1.x), 1e-12f); s1.y = 1.0f / fmaxf(sqrtf(q1.y), 1e-12f);
    s1.z = 1.0f / fmaxf(sqrtf(q1.z), 1e-12f); s1.w = 1.0f / fmaxf(sqrtf(q1.w), 1e-12f);
    u16x8 t;
    t[0] = f2bf(v0.x * s0.x * scl); t[1] = f2bf(v0.y * s0.y * scl);
    t[2] = f2bf(v0.z * s0.z * scl); t[3] = f2bf(v0.w * s0.w * scl);
    t[4] = f2bf(v1.x * s1.x * scl); t[5] = f2bf(v1.y * s1.y * scl);
    t[6] = f2bf(v1.z * s1.z * scl); t[7] = f2bf(v1.w * s1.w * scl);
    *(u16x8*)((isK ? ks : qs) + rem) = t;
}

// ---------------------------------------------------------------------------
// MFMA flash attention, split-K over keys (2 splits x 512 keys).
// Cosine attention: sim in [-10,10] -> FIXED softmax shift M=10.5 (exact).
// No running max, no per-tile row-sum shuffles: lane-local l partials,
// one cross-lane reduce at the end. Zero cross-lane ops in the main loop.
// Partials: po fp32 [split][bh][row][d] (unnormalized), pml = l per row.
// ---------------------------------------------------------------------------
__global__ __launch_bounds__(256)
void attn_mfma_kernel(const unsigned short* __restrict__ qs,
                      const unsigned short* __restrict__ ks,
                      const unsigned short* __restrict__ vb,
                      float* __restrict__ po, float* __restrict__ pml) {
    const int hw = blockIdx.x;                    // 1024 blocks
    const int virt = (hw & 7) * 128 + (hw >> 3);  // XCD-chunked: 8 bh per XCD
    const int bh = virt >> 4;
    const int sub = virt & 15;
    const int it = sub & 7;
    const int js = sub >> 3;                      // key-split index
    const int b = bh >> 3, h = bh & 7;

    const int lane = threadIdx.x & 63;
    const int wave = threadIdx.x >> 6;
    const int lo = lane & 15;
    const int hi = lane >> 4;
    const int iw = it * 128 + wave * 32;

    const unsigned short* qbh = qs + (size_t)bh * NTOK * DHEAD;
    const unsigned short* kbh = ks + (size_t)bh * NTOK * DHEAD;
    const unsigned short* vbh = vb + ((size_t)b * HIDDEN + h * DHEAD) * NTOK;

    __shared__ unsigned short Plds[4][2048];      // 32x64 bf16 per wave, swizzled
    __shared__ float Tlds[4][16][68];             // epilogue transpose
    char* pbase = (char*)&Plds[wave][0];

    bf16x8 aQ[2][2];
    #pragma unroll
    for (int f = 0; f < 2; ++f) {
        const unsigned short* qp = qbh + (size_t)(iw + f * 16 + lo) * DHEAD + hi * 8;
        aQ[f][0] = *(const bf16x8*)qp;
        aQ[f][1] = *(const bf16x8*)(qp + 32);
    }

    float lsum[2][4];
    #pragma unroll
    for (int f = 0; f < 2; ++f)
        #pragma unroll
        for (int r = 0; r < 4; ++r) lsum[f][r] = 0.0f;
    f32x4 acc[2][4];
    #pragma unroll
    for (int f = 0; f < 2; ++f)
        #pragma unroll
        for (int ds = 0; ds < 4; ++ds) acc[f][ds] = (f32x4){0.f, 0.f, 0.f, 0.f};

    for (int jt = 0; jt < 8; ++jt) {
        const int j0 = js * 512 + jt * 64;

        // --- V fragment loads issued EARLY (independent of QK)
        bf16x8 bV[4][2];
        #pragma unroll
        for (int ds = 0; ds < 4; ++ds) {
            const unsigned short* vp = vbh + (size_t)(ds * 16 + lo) * NTOK + j0 + hi * 8;
            bV[ds][0] = *(const bf16x8*)vp;
            bV[ds][1] = *(const bf16x8*)(vp + 32);
        }

        // --- K fragment loads (all 8 up front, pipelined)
        bf16x8 bK[4][2];
        #pragma unroll
        for (int jj = 0; jj < 4; ++jj) {
            const unsigned short* kp = kbh + (size_t)(j0 + jj * 16 + lo) * DHEAD + hi * 8;
            bK[jj][0] = *(const bf16x8*)kp;
            bK[jj][1] = *(const bf16x8*)(kp + 32);
        }

        // --- QK^T: sim 32x64 per wave
        f32x4 s[2][4];
        __builtin_amdgcn_s_setprio(1);
        #pragma unroll
        for (int jj = 0; jj < 4; ++jj)
            #pragma unroll
            for (int f = 0; f < 2; ++f) {
                f32x4 c = (f32x4){0.f, 0.f, 0.f, 0.f};
                c = __builtin_amdgcn_mfma_f32_16x16x32_bf16(aQ[f][0], bK[jj][0], c, 0, 0, 0);
                c = __builtin_amdgcn_mfma_f32_16x16x32_bf16(aQ[f][1], bK[jj][1], c, 0, 0, 0);
                s[f][jj] = c;
            }
        __builtin_amdgcn_s_setprio(0);

        // --- p = exp(s - 10.5): no max, no shuffles; lane-local l accumulation
        #pragma unroll
        for (int f = 0; f < 2; ++f)
            #pragma unroll
            for (int jj = 0; jj < 4; ++jj)
                #pragma unroll
                for (int r = 0; r < 4; ++r) {
                    const float p = __builtin_amdgcn_exp2f(fmaf(s[f][jj][r], LOG2E, MBIAS));
                    lsum[f][r] += p;
                    const int row = f * 16 + hi * 4 + r;
                    const int byte = (row * 128 + (jj * 16 + lo) * 2) ^ ((row & 7) << 4);
                    *(unsigned short*)(pbase + byte) = f2bf(p);
                }

        // --- P A-fragments + PV
        bf16x8 aP[2][2];
        #pragma unroll
        for (int f = 0; f < 2; ++f) {
            const int row = f * 16 + lo;
            const int swz = (lo & 7) << 4;
            aP[f][0] = *(const bf16x8*)(pbase + ((row * 128 + hi * 16) ^ swz));
            aP[f][1] = *(const bf16x8*)(pbase + ((row * 128 + 64 + hi * 16) ^ swz));
        }
        __builtin_amdgcn_s_setprio(1);
        #pragma unroll
        for (int ds = 0; ds < 4; ++ds)
            #pragma unroll
            for (int f = 0; f < 2; ++f) {
                acc[f][ds] = __builtin_amdgcn_mfma_f32_16x16x32_bf16(aP[f][0], bV[ds][0], acc[f][ds], 0, 0, 0);
                acc[f][ds] = __builtin_amdgcn_mfma_f32_16x16x32_bf16(aP[f][1], bV[ds][1], acc[f][ds], 0, 0, 0);
            }
        __builtin_amdgcn_s_setprio(0);
    }

    // --- ONE cross-lane reduce for l (over the 16 lo-lanes of each row)
    #pragma unroll
    for (int off = 1; off < 16; off <<= 1)
        #pragma unroll
        for (int f = 0; f < 2; ++f)
            #pragma unroll
            for (int r = 0; r < 4; ++r)
                lsum[f][r] += __shfl_xor(lsum[f][r], off, 64);

    // --- epilogue: store UNNORMALIZED partials + l
    float* pob = po + ((size_t)(js * 64 + bh) * NTOK + iw) * DHEAD;
    #pragma unroll
    for (int f = 0; f < 2; ++f) {
        #pragma unroll
        for (int ds = 0; ds < 4; ++ds)
            #pragma unroll
            for (int r = 0; r < 4; ++r)
                Tlds[wave][hi * 4 + r][ds * 16 + lo] = acc[f][ds][r];
        // wave-synchronous readback: fully-coalesced float4 rows
        #pragma unroll
        for (int pass = 0; pass < 4; ++pass) {
            const int flat = pass * 64 + lane;
            const int row = flat >> 4, dq = flat & 15;
            float4 v = *(float4*)&Tlds[wave][row][dq * 4];
            *(float4*)(pob + (size_t)(f * 16 + row) * DHEAD + dq * 4) = v;
        }
        if (lo == 0) {
            #pragma unroll
            for (int r = 0; r < 4; ++r) {
                const int row = iw + f * 16 + hi * 4 + r;
                pml[(size_t)(js * 64 + bh) * NTOK + row] = lsum[f][r];
            }
        }
    }
}

// ---------------------------------------------------------------------------
// Combine the two key-split partials -> attn_t bf16 token-major [b][n][512].
// Shared fixed shift => out = (o1+o2) / (l1+l2).
// ---------------------------------------------------------------------------
__global__ __launch_bounds__(256)
void combine_kernel(const float* __restrict__ po, const float* __restrict__ pml,
                    unsigned short* __restrict__ attn_t) {
    const size_t fl = ((size_t)blockIdx.x * 256 + threadIdx.x) * 4;
    const int bh  = (int)(fl >> 16);
    const int rem = (int)(fl & 65535);
    const int row = rem >> 6;
    const int d   = rem & 63;
    const int b = bh >> 3, h = bh & 7;
    const size_t SS = (size_t)64 * NTOK * DHEAD;

    const float l1 = pml[(size_t)bh * NTOK + row];
    const float l2 = pml[(size_t)(64 + bh) * NTOK + row];
    const float inv = 1.0f / (l1 + l2);

    const float4 o1 = *(const float4*)(po + fl);
    const float4 o2 = *(const float4*)(po + SS + fl);
    u16x4 r;
    r[0] = f2bf((o1.x + o2.x) * inv);
    r[1] = f2bf((o1.y + o2.y) * inv);
    r[2] = f2bf((o1.z + o2.z) * inv);
    r[3] = f2bf((o1.w + o2.w) * inv);
    *(u16x4*)(attn_t + ((size_t)b * NTOK + row) * HIDDEN + h * DHEAD + d) = r;
}

// ---------------------------------------------------------------------------
// GEMM2: out = w_out (256x512) x attn_t^T + bias, bf16 MFMA.
// ---------------------------------------------------------------------------
__global__ __launch_bounds__(128)
void gemm2_kernel(const unsigned short* __restrict__ wob,
                  const unsigned short* __restrict__ attn_t,
                  const float* __restrict__ b_out,
                  float* __restrict__ out) {
    const int b  = blockIdx.z;
    const int bm = blockIdx.y * 64;
    const int bn = blockIdx.x * 128;
    const int wave = threadIdx.x >> 6, lane = threadIdx.x & 63;
    const int lo = lane & 15, hi = lane >> 4;
    const int wn = bn + wave * 64;

    const unsigned short* Ab = wob + (size_t)(bm + lo) * HIDDEN + hi * 8;
    const unsigned short* Bb = attn_t + ((size_t)b * NTOK + wn + lo) * HIDDEN + hi * 8;

    f32x4 acc[4][4];
    #pragma unroll
    for (int mi = 0; mi < 4; ++mi)
        #pragma unroll
        for (int ni = 0; ni < 4; ++ni) acc[mi][ni] = (f32x4){0.f, 0.f, 0.f, 0.f};

    for (int k0 = 0; k0 < HIDDEN; k0 += 32) {
        bf16x8 a[4], bf[4];
        #pragma unroll
        for (int mi = 0; mi < 4; ++mi) a[mi]  = *(const bf16x8*)(Ab + (size_t)mi * 16 * HIDDEN + k0);
        #pragma unroll
        for (int ni = 0; ni < 4; ++ni) bf[ni] = *(const bf16x8*)(Bb + (size_t)ni * 16 * HIDDEN + k0);
        #pragma unroll
        for (int mi = 0; mi < 4; ++mi)
            #pragma unroll
            for (int ni = 0; ni < 4; ++ni)
                acc[mi][ni] = __builtin_amdgcn_mfma_f32_16x16x32_bf16(a[mi], bf[ni], acc[mi][ni], 0, 0, 0);
    }

    __shared__ float OL[2][32][69];
    #pragma unroll
    for (int half = 0; half < 2; ++half) {
        #pragma unroll
        for (int mm = 0; mm < 2; ++mm) {
            const int mi = half * 2 + mm;
            #pragma unroll
            for (int ni = 0; ni < 4; ++ni)
                #pragma unroll
                for (int r = 0; r < 4; ++r)
                    OL[wave][mm * 16 + hi * 4 + r][ni * 16 + lo] = acc[mi][ni][r];
        }
        #pragma unroll
        for (int i = 0; i < 8; ++i) {
            const int flat = i * 64 + lane;
            const int row = flat >> 4, c = flat & 15;
            float4 v = *(float4*)&OL[wave][row][c * 4];
            const int m = bm + half * 32 + row;
            const float bb = b_out[m];
            v.x += bb; v.y += bb; v.z += bb; v.w += bb;
            *(float4*)(out + ((size_t)b * CIN + m) * NTOK + wn + c * 4) = v;
        }
    }
}

// ---------------------------------------------------------------------------
// Launcher. WS layout (64.6 MB peak):
//  xt @0 (4.19M) | wqb @4194304 | wob @4980736 | ss @5242880 (32K) |
//  qs @5308416 (8.39M, attn_t aliased after attn) | ks @13697024 (8.39M) |
//  vb @22085632 (8.39M) | qt @30474240 (33.55M, po aliased after scale_cvt) |
//  pml @64028672 (512K)
// ---------------------------------------------------------------------------
extern "C" void kernel_launch(void* const* d_in, const int* in_sizes, int n_in,
                              void* d_out, int out_size, void* d_ws, size_t ws_size,
                              hipStream_t stream) {
    const float* x     = (const float*)d_in[0];
    const float* w_qkv = (const float*)d_in[1];
    const float* w_out = (const float*)d_in[2];
    const float* b_out = (const float*)d_in[3];
    float* out = (float*)d_out;

    char* ws = (char*)d_ws;
    unsigned short* xt  = (unsigned short*)(ws);
    unsigned short* wqb = (unsigned short*)(ws + 4194304);
    unsigned short* wob = (unsigned short*)(ws + 4980736);
    float*          ss  = (float*)(ws + 5242880);
    unsigned short* qs  = (unsigned short*)(ws + 5308416);
    unsigned short* ks  = (unsigned short*)(ws + 13697024);
    unsigned short* vb  = (unsigned short*)(ws + 22085632);
    float*          qt  = (float*)(ws + 30474240);
    float*          po  = (float*)(ws + 30474240);               // aliases qt (dead)
    unsigned short* attn_t = (unsigned short*)(ws + 5308416);    // aliases qs (dead)
    float*          pml = (float*)(ws + 64028672);

    hipMemsetAsync(ss, 0, 8 * 1024 * sizeof(float), stream);

    cvt_x_kernel<<<dim3(16, 4, 8), 256, 0, stream>>>(x, xt);
    cvt_w_kernel<<<256, 256, 0, stream>>>(w_qkv, w_out, wqb, wob);

    gemm1_kernel<<<dim3(8, 12, 8), 256, 0, stream>>>(wqb, xt, qt, vb, ss);

    scale_cvt_kernel<<<4096, 256, 0, stream>>>(qt, ss, qs, ks);

    attn_mfma_kernel<<<1024, 256, 0, stream>>>(qs, ks, vb, po, pml);

    combine_kernel<<<4096, 256, 0, stream>>>(po, pml, attn_t);

    gemm2_kernel<<<dim3(8, 4, 8), 128, 0, stream>>>(wob, attn_t, b_out, out);
}